// Round 4
// baseline (2065.708 us; speedup 1.0000x reference)
//
#include <hip/hip_runtime.h>
#include <stdint.h>

#define NSEQ 256
#define LRES 384
#define NH   8
#define NL   (NSEQ*LRES)              // 98304 msa rows
#define SCALE 0.17677669529663687f    // 1/sqrt(32)

typedef unsigned short u16;
typedef unsigned int   u32;

// ---------- bf16 helpers ----------
__device__ __forceinline__ u16 f2bf(float f) {
    u32 x = __float_as_uint(f);
    return (u16)((x + 0x7fffu + ((x >> 16) & 1u)) >> 16);
}
__device__ __forceinline__ u32 pack2(float a, float b) {
    u32 xa = __float_as_uint(a);
    u32 xb = __float_as_uint(b);
    xa = (xa + 0x7fffu + ((xa >> 16) & 1u)) >> 16;
    xb = ((xb + 0x7fffu + ((xb >> 16) & 1u)) >> 16) << 16;
    return xa | xb;
}
__device__ __forceinline__ uint4 pack8(const float f[8]) {
    uint4 r;
    r.x = pack2(f[0], f[1]); r.y = pack2(f[2], f[3]);
    r.z = pack2(f[4], f[5]); r.w = pack2(f[6], f[7]);
    return r;
}
__device__ __forceinline__ void unpack2(u32 u, float& f0, float& f1) {
    f0 = __uint_as_float((u & 0xffffu) << 16);
    f1 = __uint_as_float(u & 0xffff0000u);
}
__device__ __forceinline__ void unpack8(uint4 p, float f[8]) {
    unpack2(p.x, f[0], f[1]);
    unpack2(p.y, f[2], f[3]);
    unpack2(p.z, f[4], f[5]);
    unpack2(p.w, f[6], f[7]);
}

// ---------- wave-64 reductions ----------
__device__ __forceinline__ float wred_sum(float v) {
#pragma unroll
    for (int o = 32; o > 0; o >>= 1) v += __shfl_xor(v, o, 64);
    return v;
}
__device__ __forceinline__ float wred_max(float v) {
#pragma unroll
    for (int o = 32; o > 0; o >>= 1) v = fmaxf(v, __shfl_xor(v, o, 64));
    return v;
}

// =====================================================================
// K0: per-row LayerNorm stats of msa (fp32). 1 wave/row, 4 rows/blk.
// =====================================================================
__global__ __launch_bounds__(256) void rowstats_k(
    const float* __restrict__ x, float* __restrict__ stats)
{
    const int lane = threadIdx.x & 63;
    const int row = blockIdx.x * 4 + (threadIdx.x >> 6);
    const size_t base = (size_t)row * 256 + lane * 4;
    float4 v = *(const float4*)(x + base);
    float s  = wred_sum(v.x + v.y + v.z + v.w);
    float sq = wred_sum(v.x*v.x + v.y*v.y + v.z*v.z + v.w*v.w);
    if (lane == 0) {
        float mu  = s * (1.f / 256.f);
        float var = sq * (1.f / 256.f) - mu * mu;
        stats[(size_t)row * 2]     = mu;
        stats[(size_t)row * 2 + 1] = rsqrtf(var + 1e-5f);
    }
}

// =====================================================================
// K1: C(Mx256) = [LN](A)(Mx256) @ W(256x256, fp32) [+bias][epilogue]
// A is fp32 (msa) or bf16 (intermediate) per a_bf16 flag.
// tile 64x128 (blockIdx.y picks column half), 256 thr, 4x8/thr.
// =====================================================================
enum { MODE_KSW = 0, MODE_QSW = 1, MODE_QT = 2, MODE_KT = 3,
       MODE_VT = 4, MODE_GATE = 5, MODE_OUT = 6 };

__global__ __launch_bounds__(256) void gemm_ln_k(
    const void* __restrict__ Av, int a_bf16,
    const float* __restrict__ stats,
    const float* __restrict__ lng, const float* __restrict__ lnb,
    const float* __restrict__ W, const float* __restrict__ bias,
    void* __restrict__ out, const float* __restrict__ seqw, int mode)
{
    __shared__ float As_t[32][68];   // [k][row]
    __shared__ float Ws[32][132];    // [k][col]
    __shared__ float gs[256], bs[256];
    const int tid = threadIdx.x;
    const int bx = blockIdx.y;       // column half
    const int by = blockIdx.x;       // row tile
    const int tx = tid & 15, ty = tid >> 4;
    const int ar = tid >> 2, acg = tid & 3;
    const int wr = tid >> 3, wcg = tid & 7;
    const bool do_ln = (stats != nullptr);

    if (do_ln) { gs[tid] = lng[tid]; bs[tid] = lnb[tid]; }
    __syncthreads();

    const int arow_idx = by * 64 + ar;
    float mu = 0.f, rsg = 0.f;
    if (do_ln) {
        mu  = stats[(size_t)arow_idx * 2];
        rsg = stats[(size_t)arow_idx * 2 + 1];
    }

    float acc[4][8];
#pragma unroll
    for (int i = 0; i < 4; ++i)
#pragma unroll
        for (int j = 0; j < 8; ++j) acc[i][j] = 0.f;

    const size_t arow = (size_t)arow_idx * 256 + acg * 8;

    for (int kk = 0; kk < 256; kk += 32) {
        float af[8];
        if (a_bf16) {
            uint4 a8 = *(const uint4*)((const u16*)Av + arow + kk);
            unpack8(a8, af);
        } else {
            float4 x0 = *(const float4*)((const float*)Av + arow + kk);
            float4 x1 = *(const float4*)((const float*)Av + arow + kk + 4);
            af[0] = x0.x; af[1] = x0.y; af[2] = x0.z; af[3] = x0.w;
            af[4] = x1.x; af[5] = x1.y; af[6] = x1.z; af[7] = x1.w;
        }
        const float* wrow = W + (size_t)(kk + wr) * 256 + bx * 128 + wcg * 16;
        float4 w0 = *(const float4*)(wrow);
        float4 w1 = *(const float4*)(wrow + 4);
        float4 w2 = *(const float4*)(wrow + 8);
        float4 w3 = *(const float4*)(wrow + 12);
        if (do_ln) {
#pragma unroll
            for (int j = 0; j < 8; ++j) {
                const int k = kk + acg * 8 + j;
                af[j] = (af[j] - mu) * rsg * gs[k] + bs[k];
            }
        }
        __syncthreads();
#pragma unroll
        for (int j = 0; j < 8; ++j) As_t[acg * 8 + j][ar] = af[j];
        float* wsrow = &Ws[wr][wcg * 16];
        *(float4*)(wsrow)      = w0;
        *(float4*)(wsrow + 4)  = w1;
        *(float4*)(wsrow + 8)  = w2;
        *(float4*)(wsrow + 12) = w3;
        __syncthreads();
#pragma unroll 8
        for (int k = 0; k < 32; ++k) {
            const float4 a  = *(const float4*)&As_t[k][ty * 4];
            const float4 b0 = *(const float4*)&Ws[k][tx * 8];
            const float4 b1 = *(const float4*)&Ws[k][tx * 8 + 4];
            const float av[4] = {a.x, a.y, a.z, a.w};
            const float bv[8] = {b0.x, b0.y, b0.z, b0.w, b1.x, b1.y, b1.z, b1.w};
#pragma unroll
            for (int i = 0; i < 4; ++i)
#pragma unroll
                for (int j = 0; j < 8; ++j)
                    acc[i][j] = fmaf(av[i], bv[j], acc[i][j]);
        }
    }

    const int gc0 = bx * 128 + tx * 8;
    float bias8[8] = {0.f, 0.f, 0.f, 0.f, 0.f, 0.f, 0.f, 0.f};
    if (bias) {
#pragma unroll
        for (int j = 0; j < 8; ++j) bias8[j] = bias[gc0 + j];
    }

    if (mode == MODE_QSW) {
        float* o = (float*)out;
#pragma unroll
        for (int i = 0; i < 4; ++i) {
            const size_t gr = (size_t)by * 64 + ty * 4 + i;
#pragma unroll
            for (int j = 0; j < 8; ++j)
                o[gr * 256 + gc0 + j] = (acc[i][j] + bias8[j]) * SCALE;
        }
    } else if (mode == MODE_OUT) {
        // FINAL OUTPUT: fp32 (reference returns float32; d_out is float*)
        float* o = (float*)out;
#pragma unroll
        for (int i = 0; i < 4; ++i) {
            const size_t gr = (size_t)by * 64 + ty * 4 + i;
            float f[8];
#pragma unroll
            for (int j = 0; j < 8; ++j) f[j] = acc[i][j] + bias8[j];
            *(float4*)(o + gr * 256 + gc0)     = make_float4(f[0], f[1], f[2], f[3]);
            *(float4*)(o + gr * 256 + gc0 + 4) = make_float4(f[4], f[5], f[6], f[7]);
        }
    } else if (mode == MODE_KSW || mode == MODE_GATE) {
        u16* o = (u16*)out;
#pragma unroll
        for (int i = 0; i < 4; ++i) {
            const size_t gr = (size_t)by * 64 + ty * 4 + i;
            float f[8];
#pragma unroll
            for (int j = 0; j < 8; ++j) {
                float v = acc[i][j] + bias8[j];
                if (mode == MODE_GATE) v = 1.f / (1.f + __expf(-v));
                f[j] = v;
            }
            *(uint4*)(o + gr * 256 + gc0) = pack8(f);
        }
    } else {  // MODE_QT / MODE_KT / MODE_VT : store to [h][i][n*32+d]
        u16* o = (u16*)out;
        const int h = gc0 >> 5, dlo = gc0 & 31;
#pragma unroll
        for (int i = 0; i < 4; ++i) {
            const int gr = by * 64 + ty * 4 + i;
            const int n = gr / LRES, ii = gr % LRES;
            float mult = (mode == MODE_QT) ? seqw[(size_t)gr * NH + h]
                        : (mode == MODE_KT ? SCALE : 1.f);
            float f[8];
#pragma unroll
            for (int j = 0; j < 8; ++j) f[j] = acc[i][j] * mult;
            *(uint4*)(o + (size_t)h * 3145728 + (size_t)ii * 8192 + n * 32 + dlo) = pack8(f);
        }
    }
}

// =====================================================================
// K2: sw_logits[(n*384+i)*8+h] = dot32(qsw[i,h*32:], ksw[n*384+i, h*32:])
// qsw fp32 (ours), ksw bf16 (ours).
// =====================================================================
__global__ __launch_bounds__(256) void swl_dot_k(
    const float* __restrict__ qsw, const u16* __restrict__ ksw,
    float* __restrict__ swl)
{
    const int gid = blockIdx.x * 256 + threadIdx.x;  // < NL*NH
    const int r = gid >> 3, h = gid & 7;
    const int i = r % LRES;
    const float* qp = qsw + (size_t)i * 256 + h * 32;
    const uint4* kp = (const uint4*)(ksw + (size_t)r * 256 + h * 32);
    float s = 0.f;
#pragma unroll
    for (int g4 = 0; g4 < 4; ++g4) {
        float kf[8]; unpack8(kp[g4], kf);
#pragma unroll
        for (int j = 0; j < 8; ++j) s += qp[g4 * 8 + j] * kf[j];
    }
    swl[gid] = s;
}

// =====================================================================
// K3: softmax over n (stride 3072) per (i,h) column. Wave per column.
// =====================================================================
__global__ __launch_bounds__(256) void softmax_n_k(float* __restrict__ swl)
{
    const int col = blockIdx.x * 4 + (threadIdx.x >> 6);  // i*8+h
    const int lane = threadIdx.x & 63;
    float* base = swl + col;
    float v[4];
#pragma unroll
    for (int t = 0; t < 4; ++t) v[t] = base[(size_t)(lane * 4 + t) * 3072];
    float mx = wred_max(fmaxf(fmaxf(v[0], v[1]), fmaxf(v[2], v[3])));
    float e[4], s = 0.f;
#pragma unroll
    for (int t = 0; t < 4; ++t) { e[t] = __expf(v[t] - mx); s += e[t]; }
    s = wred_sum(s);
    const float inv = 1.f / s;
#pragma unroll
    for (int t = 0; t < 4; ++t) base[(size_t)(lane * 4 + t) * 3072] = e[t] * inv;
}

// =====================================================================
// K4: biasH[(i*384+j)*8+h] = (LN(pair[i,j,:]) @ Wb)[h]. Wave per (i,j).
// =====================================================================
__global__ __launch_bounds__(256) void pair_bias_k(
    const float* __restrict__ pair, const float* __restrict__ g,
    const float* __restrict__ b, const float* __restrict__ Wb,
    float* __restrict__ biasH)
{
    const int lane = threadIdx.x & 63;
    const size_t rp = (size_t)blockIdx.x * 4 + (threadIdx.x >> 6);
    float2 u = *(const float2*)(pair + rp * 128 + lane * 2);
    float f0 = u.x, f1 = u.y;
    float s  = wred_sum(f0 + f1);
    float sq = wred_sum(f0 * f0 + f1 * f1);
    float mu  = s * (1.f / 128.f);
    float var = sq * (1.f / 128.f) - mu * mu;
    float rs  = rsqrtf(var + 1e-5f);
    const int c0 = lane * 2;
    float xn0 = (f0 - mu) * rs * g[c0]     + b[c0];
    float xn1 = (f1 - mu) * rs * g[c0 + 1] + b[c0 + 1];
    float4 wa0 = *(const float4*)(Wb + (size_t)c0 * 8);
    float4 wa1 = *(const float4*)(Wb + (size_t)c0 * 8 + 4);
    float4 wb0 = *(const float4*)(Wb + (size_t)(c0 + 1) * 8);
    float4 wb1 = *(const float4*)(Wb + (size_t)(c0 + 1) * 8 + 4);
    const float wa[8] = {wa0.x, wa0.y, wa0.z, wa0.w, wa1.x, wa1.y, wa1.z, wa1.w};
    const float wb_[8] = {wb0.x, wb0.y, wb0.z, wb0.w, wb1.x, wb1.y, wb1.z, wb1.w};
    float acc[8];
#pragma unroll
    for (int h = 0; h < 8; ++h) acc[h] = wred_sum(xn0 * wa[h] + xn1 * wb_[h]);
    if (lane == 0) {
#pragma unroll
        for (int h = 0; h < 8; ++h) biasH[rp * 8 + h] = acc[h];
    }
}

// =====================================================================
// K5: partials[kc][h][i][j] = sum_{k in kc-slice} Q_h[i,k]*K_h[j,k]
// NT GEMM K=8192 over bf16 intermediates, split-K=4 slabs (no atomics).
// =====================================================================
__global__ __launch_bounds__(256) void gemm_logits_k(
    const u16* __restrict__ qT, const u16* __restrict__ kT,
    float* __restrict__ part)
{
    __shared__ float As_t[32][68];
    __shared__ float Bs_t[32][132];
    int bid = blockIdx.x;
    const int bi = bid % 6; bid /= 6;
    const int bj = bid % 3; bid /= 3;
    const int h  = bid % 8;
    const int kc = bid / 8;
    const u16* A = qT + (size_t)h * 3145728 + (size_t)bi * 64 * 8192;
    const u16* B = kT + (size_t)h * 3145728 + (size_t)bj * 128 * 8192;
    const int tid = threadIdx.x;
    const int tx = tid & 15, ty = tid >> 4;
    const int ar = tid >> 2, acg = tid & 3;
    const int br = tid >> 1, bkg = tid & 1;

    float acc[4][8];
#pragma unroll
    for (int i = 0; i < 4; ++i)
#pragma unroll
        for (int j = 0; j < 8; ++j) acc[i][j] = 0.f;

    const int k0beg = kc * 2048, k0end = k0beg + 2048;
    for (int k0 = k0beg; k0 < k0end; k0 += 32) {
        uint4 a8 = *(const uint4*)(A + (size_t)ar * 8192 + k0 + acg * 8);
        uint4 b0 = *(const uint4*)(B + (size_t)br * 8192 + k0 + bkg * 16);
        uint4 b1 = *(const uint4*)(B + (size_t)br * 8192 + k0 + bkg * 16 + 8);
        __syncthreads();
        float af[8]; unpack8(a8, af);
#pragma unroll
        for (int j = 0; j < 8; ++j) As_t[acg * 8 + j][ar] = af[j];
        float bf8[8]; unpack8(b0, bf8);
#pragma unroll
        for (int j = 0; j < 8; ++j) Bs_t[bkg * 16 + j][br] = bf8[j];
        unpack8(b1, bf8);
#pragma unroll
        for (int j = 0; j < 8; ++j) Bs_t[bkg * 16 + 8 + j][br] = bf8[j];
        __syncthreads();
#pragma unroll 8
        for (int k = 0; k < 32; ++k) {
            const float4 a   = *(const float4*)&As_t[k][ty * 4];
            const float4 b0v = *(const float4*)&Bs_t[k][tx * 8];
            const float4 b1v = *(const float4*)&Bs_t[k][tx * 8 + 4];
            const float av[4] = {a.x, a.y, a.z, a.w};
            const float bv[8] = {b0v.x, b0v.y, b0v.z, b0v.w, b1v.x, b1v.y, b1v.z, b1v.w};
#pragma unroll
            for (int i = 0; i < 4; ++i)
#pragma unroll
                for (int j = 0; j < 8; ++j)
                    acc[i][j] = fmaf(av[i], bv[j], acc[i][j]);
        }
    }
    float* dst = part + (size_t)kc * 1179648 + (size_t)h * 147456
               + (size_t)(bi * 64) * 384 + bj * 128;
#pragma unroll
    for (int i = 0; i < 4; ++i)
#pragma unroll
        for (int j = 0; j < 8; ++j)
            dst[(size_t)(ty * 4 + i) * 384 + tx * 8 + j] = acc[i][j];
}

// =====================================================================
// K6: attn[h,i,:] = softmax_j( sum_kc part[kc,h,i,:] + biasH[i,:,h] )
// =====================================================================
__global__ __launch_bounds__(256) void softmax_j_k(
    const float* __restrict__ part, const float* __restrict__ biasH,
    u16* __restrict__ attnB)
{
    const int row = blockIdx.x * 4 + (threadIdx.x >> 6);  // h*384+i
    const int lane = threadIdx.x & 63;
    const int h = row / LRES, i = row % LRES;
    const float* p = part + (size_t)h * 147456 + (size_t)i * 384;
    const float* bh = biasH + (size_t)i * 3072 + h;
    float v[6];
#pragma unroll
    for (int t = 0; t < 6; ++t) {
        const int j = t * 64 + lane;
        v[t] = p[j] + p[j + 1179648] + p[j + 2359296] + p[j + 3538944]
             + bh[(size_t)j * 8];
    }
    float mx = v[0];
#pragma unroll
    for (int t = 1; t < 6; ++t) mx = fmaxf(mx, v[t]);
    mx = wred_max(mx);
    float e[6], s = 0.f;
#pragma unroll
    for (int t = 0; t < 6; ++t) { e[t] = __expf(v[t] - mx); s += e[t]; }
    s = wred_sum(s);
    const float inv = 1.f / s;
    u16* ab = attnB + (size_t)h * 147456 + (size_t)i * 384;
#pragma unroll
    for (int t = 0; t < 6; ++t) ab[t * 64 + lane] = f2bf(e[t] * inv);
}

// =====================================================================
// K7: per head O_h(384x8192) = attn_h(384x384) @ V_h(384x8192);
// epilogue: gate buffer updated IN PLACE: g <- O * g
// (each element read+written by exactly one thread; no restrict)
// =====================================================================
__global__ __launch_bounds__(256) void gemm_out_k(
    const u16* __restrict__ attnB, const u16* __restrict__ vT,
    u16* gate_io)
{
    __shared__ float As_t[32][68];
    __shared__ float Bs[32][132];
    int bid = blockIdx.x;
    const int bi = bid % 6; bid /= 6;
    const int bn = bid % 64;
    const int h  = bid / 64;
    const u16* A = attnB + (size_t)h * 147456 + (size_t)bi * 64 * 384;
    const u16* B = vT + (size_t)h * 3145728 + bn * 128;
    const int tid = threadIdx.x;
    const int tx = tid & 15, ty = tid >> 4;
    const int ar = tid >> 2, acg = tid & 3;
    const int brr = tid >> 3, bcg = tid & 7;

    float acc[4][8];
#pragma unroll
    for (int i = 0; i < 4; ++i)
#pragma unroll
        for (int j = 0; j < 8; ++j) acc[i][j] = 0.f;

    for (int k0 = 0; k0 < 384; k0 += 32) {
        uint4 a8 = *(const uint4*)(A + (size_t)ar * 384 + k0 + acg * 8);
        uint4 b0 = *(const uint4*)(B + (size_t)(k0 + brr) * 8192 + bcg * 16);
        uint4 b1 = *(const uint4*)(B + (size_t)(k0 + brr) * 8192 + bcg * 16 + 8);
        __syncthreads();
        float af[8]; unpack8(a8, af);
#pragma unroll
        for (int j = 0; j < 8; ++j) As_t[acg * 8 + j][ar] = af[j];
        float bf8[8]; unpack8(b0, bf8);
#pragma unroll
        for (int j = 0; j < 8; ++j) Bs[brr][bcg * 16 + j] = bf8[j];
        unpack8(b1, bf8);
#pragma unroll
        for (int j = 0; j < 8; ++j) Bs[brr][bcg * 16 + 8 + j] = bf8[j];
        __syncthreads();
#pragma unroll 8
        for (int k = 0; k < 32; ++k) {
            const float4 a   = *(const float4*)&As_t[k][ty * 4];
            const float4 b0v = *(const float4*)&Bs[k][tx * 8];
            const float4 b1v = *(const float4*)&Bs[k][tx * 8 + 4];
            const float av[4] = {a.x, a.y, a.z, a.w};
            const float bv[8] = {b0v.x, b0v.y, b0v.z, b0v.w, b1v.x, b1v.y, b1v.z, b1v.w};
#pragma unroll
            for (int i = 0; i < 4; ++i)
#pragma unroll
                for (int j = 0; j < 8; ++j)
                    acc[i][j] = fmaf(av[i], bv[j], acc[i][j]);
        }
    }
    const int gc0 = bn * 128 + tx * 8;        // c in [0,8192)
    const int n = gc0 >> 5, dlo = gc0 & 31;
#pragma unroll
    for (int i = 0; i < 4; ++i) {
        const int gi = bi * 64 + ty * 4 + i;
        const size_t idx = ((size_t)(n * LRES + gi)) * 256 + h * 32 + dlo;
        uint4 g8 = *(const uint4*)(gate_io + idx);
        float gf[8]; unpack8(g8, gf);
        float f[8];
#pragma unroll
        for (int j = 0; j < 8; ++j) f[j] = acc[i][j] * gf[j];
        *(uint4*)(gate_io + idx) = pack8(f);
    }
}

// =====================================================================
// launcher
// =====================================================================
extern "C" void kernel_launch(void* const* d_in, const int* in_sizes, int n_in,
                              void* d_out, int out_size, void* d_ws, size_t ws_size,
                              hipStream_t stream)
{
    const float* msa       = (const float*)d_in[0];
    const float* pair      = (const float*)d_in[1];
    const float* ln_msa_g  = (const float*)d_in[2];
    const float* ln_msa_b  = (const float*)d_in[3];
    const float* ln_pair_g = (const float*)d_in[4];
    const float* ln_pair_b = (const float*)d_in[5];
    const float* Wq_sw     = (const float*)d_in[6];
    const float* bq_sw     = (const float*)d_in[7];
    const float* Wk_sw     = (const float*)d_in[8];
    const float* bk_sw     = (const float*)d_in[9];
    const float* Wq        = (const float*)d_in[10];
    const float* Wk        = (const float*)d_in[11];
    const float* Wv        = (const float*)d_in[12];
    const float* Wb        = (const float*)d_in[13];
    const float* Wg        = (const float*)d_in[14];
    const float* bg        = (const float*)d_in[15];
    const float* Wo        = (const float*)d_in[16];
    const float* bo        = (const float*)d_in[17];
    float* out = (float*)d_out;   // reference output dtype: float32

    char* ws = (char*)d_ws;
    u16*   slotA  = (u16*)(ws + 0);            // 50331648 B: ksw -> qT -> vT
    u16*   slotB  = (u16*)(ws + 50331648);     // 50331648 B: kT -> gate -> a2
    float* stats  = (float*)(ws + 100663296);  // NL*2 fp32
    float* qsw    = (float*)(ws + 101449728);  // 384x256 fp32
    float* swl    = (float*)(ws + 101842944);  // NL*8 fp32
    float* biasH  = (float*)(ws + 104988672);  // 384*384*8 fp32
    float* part   = (float*)(ws + 109707264);  // 4*8*384*384 fp32
    u16*   attnB  = (u16*)(ws + 128581632);    // 8*384*384 bf16
    // total: 130940928 B (~125 MiB)

    // 1. LN row stats of msa
    rowstats_k<<<NL / 4, 256, 0, stream>>>(msa, stats);
    // 2. ksw = LN(msa) @ Wk_sw + bk_sw  -> slotA (bf16)
    gemm_ln_k<<<dim3(NL / 64, 2), 256, 0, stream>>>(
        msa, 0, stats, ln_msa_g, ln_msa_b, Wk_sw, bk_sw, slotA, nullptr, MODE_KSW);
    // 3. qsw = (LN(msa[0]) @ Wq_sw + bq_sw) * scale  (fp32)
    gemm_ln_k<<<dim3(LRES / 64, 2), 256, 0, stream>>>(
        msa, 0, stats, ln_msa_g, ln_msa_b, Wq_sw, bq_sw, qsw, nullptr, MODE_QSW);
    // 4. sw_logits
    swl_dot_k<<<NL * NH / 256, 256, 0, stream>>>(qsw, slotA, swl);
    // 5. softmax over n -> seq_weight (in place)
    softmax_n_k<<<LRES * NH / 4, 256, 0, stream>>>(swl);
    // 6. qT = LN(msa) @ Wq, x seq_weight -> slotA (ksw dead)
    gemm_ln_k<<<dim3(NL / 64, 2), 256, 0, stream>>>(
        msa, 0, stats, ln_msa_g, ln_msa_b, Wq, nullptr, slotA, swl, MODE_QT);
    // 7. kT = LN(msa) @ Wk, x scale -> slotB
    gemm_ln_k<<<dim3(NL / 64, 2), 256, 0, stream>>>(
        msa, 0, stats, ln_msa_g, ln_msa_b, Wk, nullptr, slotB, nullptr, MODE_KT);
    // 8. pair bias
    pair_bias_k<<<LRES * LRES / 4, 256, 0, stream>>>(
        pair, ln_pair_g, ln_pair_b, Wb, biasH);
    // 9. logits split-K partials
    gemm_logits_k<<<6 * 3 * 8 * 4, 256, 0, stream>>>(slotA, slotB, part);
    // 10. softmax over j (reduce partials + bias) -> attn bf16
    softmax_j_k<<<NH * LRES / 4, 256, 0, stream>>>(part, biasH, attnB);
    // 11. vT = LN(msa) @ Wv -> slotA (qT dead)
    gemm_ln_k<<<dim3(NL / 64, 2), 256, 0, stream>>>(
        msa, 0, stats, ln_msa_g, ln_msa_b, Wv, nullptr, slotA, nullptr, MODE_VT);
    // 12. gate = sigmoid(LN(msa) @ Wg + bg) -> slotB (kT dead)
    gemm_ln_k<<<dim3(NL / 64, 2), 256, 0, stream>>>(
        msa, 0, stats, ln_msa_g, ln_msa_b, Wg, bg, slotB, nullptr, MODE_GATE);
    // 13. attn @ V, gate applied IN PLACE in slotB
    gemm_out_k<<<6 * 64 * 8, 256, 0, stream>>>(attnB, slotA, slotB);
    // 14. out = a2 @ Wo + bo (no LN), A is bf16 intermediate -> fp32 out
    gemm_ln_k<<<dim3(NL / 64, 2), 256, 0, stream>>>(
        slotB, 1, nullptr, nullptr, nullptr, Wo, bo, out, nullptr, MODE_OUT);
}